// Round 12
// baseline (486.042 us; speedup 1.0000x reference)
//
#include <hip/hip_runtime.h>

#define BN_EPS 1e-5f

typedef __attribute__((ext_vector_type(8))) short bf16x8;
typedef __attribute__((ext_vector_type(4))) float f32x4;

__device__ __forceinline__ float bf2f(unsigned short u) {
  return __uint_as_float(((unsigned int)u) << 16);
}
__device__ __forceinline__ unsigned short f2bf(float f) {
  unsigned int u = __float_as_uint(f);
  u = u + 0x7FFFu + ((u >> 16) & 1u);   // round-to-nearest-even
  return (unsigned short)(u >> 16);
}

// async global->LDS, 16B per lane; LDS dest = (wave-uniform base) + lane*16
__device__ __forceinline__ void gload16(const unsigned short* g, unsigned short* l) {
  __builtin_amdgcn_global_load_lds(
      (const __attribute__((address_space(1))) unsigned int*)g,
      (__attribute__((address_space(3))) unsigned int*)l, 16, 0, 0);
}

// ---------------- graph structure ----------------

__global__ __launch_bounds__(256) void count_boundary(const int* __restrict__ dst, int E,
                                                      int* __restrict__ counts,
                                                      const int* __restrict__ batch, int N,
                                                      unsigned int* __restrict__ gstart) {
  int e = blockIdx.x * 256 + threadIdx.x;
  if (e < E) atomicAdd(&counts[dst[e]], 1);
  if (e < N) {
    if (e == 0 || batch[e] != batch[e - 1]) atomicMin(&gstart[batch[e]], (unsigned int)e);
  }
}

__global__ __launch_bounds__(256) void scan1(const int* __restrict__ counts, int N,
                                             int* __restrict__ offs, int* __restrict__ blkSum,
                                             float* __restrict__ dinv) {
  __shared__ int sd[256];
  int t = threadIdx.x;
  int i0 = blockIdx.x * 1024 + t * 4;
  int v0 = (i0 + 0 < N) ? counts[i0 + 0] : 0;
  int v1 = (i0 + 1 < N) ? counts[i0 + 1] : 0;
  int v2 = (i0 + 2 < N) ? counts[i0 + 2] : 0;
  int v3 = (i0 + 3 < N) ? counts[i0 + 3] : 0;
  if (i0 + 0 < N) dinv[i0 + 0] = rsqrtf((float)(v0 + 1));
  if (i0 + 1 < N) dinv[i0 + 1] = rsqrtf((float)(v1 + 1));
  if (i0 + 2 < N) dinv[i0 + 2] = rsqrtf((float)(v2 + 1));
  if (i0 + 3 < N) dinv[i0 + 3] = rsqrtf((float)(v3 + 1));
  int tot = v0 + v1 + v2 + v3;
  sd[t] = tot;
  __syncthreads();
  for (int off = 1; off < 256; off <<= 1) {
    int x = (t >= off) ? sd[t - off] : 0;
    __syncthreads();
    sd[t] += x;
    __syncthreads();
  }
  int excl = sd[t] - tot;
  if (i0 + 0 < N) offs[i0 + 0] = excl;
  if (i0 + 1 < N) offs[i0 + 1] = excl + v0;
  if (i0 + 2 < N) offs[i0 + 2] = excl + v0 + v1;
  if (i0 + 3 < N) offs[i0 + 3] = excl + v0 + v1 + v2;
  if (t == 255) blkSum[blockIdx.x] = sd[255];
}

__global__ void scan2_fix(const int* __restrict__ blkSum, int nb, int* __restrict__ blkOff,
                          int* __restrict__ offs, int N,
                          unsigned int* __restrict__ gstart, int G) {
  if (blockIdx.x != 0) return;
  if (threadIdx.x == 0) {
    int run = 0;
    for (int b = 0; b < nb; ++b) { blkOff[b] = run; run += blkSum[b]; }
    offs[N] = run;
  } else if (threadIdx.x == 1) {
    gstart[G] = (unsigned int)N;
    for (int g = G - 1; g >= 0; --g)
      if (gstart[g] == 0xFFFFFFFFu) gstart[g] = gstart[g + 1];
  }
}

__global__ __launch_bounds__(1024) void scan3(int* __restrict__ offs, int N,
                                              const int* __restrict__ blkOff) {
  int i = blockIdx.x * 1024 + threadIdx.x;
  if (i < N) offs[i] += blkOff[blockIdx.x];
}

// ---------------- fill CSR + dtype conversions + pad zeroing (one dispatch) ----------------

__global__ __launch_bounds__(256) void fill_cvt(const int* __restrict__ src,
                                                const int* __restrict__ dst, int E,
                                                const int* __restrict__ offs,
                                                int* __restrict__ cursor,
                                                const float* __restrict__ dinv,
                                                int2* __restrict__ csr,
                                                const float* __restrict__ x,
                                                unsigned short* __restrict__ xb, int nx4,
                                                const float* __restrict__ W0,
                                                unsigned short* __restrict__ Wt0,
                                                const float* __restrict__ W1,
                                                unsigned short* __restrict__ Wt1,
                                                const float* __restrict__ W2,
                                                unsigned short* __restrict__ Wt2,
                                                unsigned short* __restrict__ pad128, int npad128_8,
                                                unsigned short* __restrict__ pad256, int npad256_8) {
  long long idx = (long long)blockIdx.x * 256 + threadIdx.x;
  if (idx < E) {
    int e = (int)idx;
    int s = src[e], d = dst[e];
    int pos = offs[d] + atomicAdd(&cursor[d], 1);
    csr[pos] = make_int2(s, __float_as_int(dinv[s] * dinv[d]));
    return;
  }
  idx -= E;
  if (idx < nx4) {
    float4 v = ((const float4*)x)[idx];
    unsigned int lo = (unsigned int)f2bf(v.x) | ((unsigned int)f2bf(v.y) << 16);
    unsigned int hi = (unsigned int)f2bf(v.z) | ((unsigned int)f2bf(v.w) << 16);
    ((uint2*)xb)[idx] = make_uint2(lo, hi);
    return;
  }
  idx -= nx4;
  if (idx < 128 * 256) {
    int k = (int)(idx >> 8), n = (int)(idx & 255);
    Wt0[n * 128 + k] = f2bf(W0[k * 256 + n]);
    return;
  }
  idx -= 128 * 256;
  if (idx < 256 * 256) {
    int k = (int)(idx >> 8), n = (int)(idx & 255);
    Wt1[n * 256 + k] = f2bf(W1[k * 256 + n]);
    return;
  }
  idx -= 256 * 256;
  if (idx < 256 * 256) {
    int k = (int)(idx >> 8), n = (int)(idx & 255);
    Wt2[n * 256 + k] = f2bf(W2[k * 256 + n]);
    return;
  }
  idx -= 256 * 256;
  if (idx < npad128_8) { ((uint4*)pad128)[idx] = make_uint4(0, 0, 0, 0); return; }
  idx -= npad128_8;
  if (idx < npad256_8) { ((uint4*)pad256)[idx] = make_uint4(0, 0, 0, 0); return; }
}

// ---------------- aggregation: HALF-CHANNEL passes for L2 locality ----------------
// Each pass gathers only 128 of 256 channels -> working set 12.8 MB (vs 25.6),
// raising per-XCD L2 hit rate on the random src gathers. BN scale/shift of the
// previous layer computed in an LDS prologue, applied per gathered value.
// Lane holds 2 channels (4B load): row byte offset = s*512 + HALF*256 + lane*4.

__device__ __forceinline__ void acc2(unsigned int v, float co, float2 sc, float2 sh,
                                     float& ax, float& ay) {
  float fx = fmaxf(bf2f((unsigned short)(v & 0xffff)) * sc.x + sh.x, 0.f);
  float fy = fmaxf(bf2f((unsigned short)(v >> 16)) * sc.y + sh.y, 0.f);
  ax += co * fx; ay += co * fy;
}

template <int HALF>
__global__ __launch_bounds__(256) void agg256_half(const unsigned short* __restrict__ h,
                                                   const int* __restrict__ offs,
                                                   const int2* __restrict__ csr,
                                                   const float* __restrict__ dinv,
                                                   const float* __restrict__ sums,
                                                   const float* __restrict__ sumsq,
                                                   const float* __restrict__ gamma,
                                                   const float* __restrict__ beta,
                                                   float invN,
                                                   unsigned short* __restrict__ out, int N) {
  __shared__ float s_sc[128], s_sh[128];
  if (threadIdx.x < 128) {
    int c = HALF * 128 + threadIdx.x;
    float mean = sums[c] * invN;
    float var = sumsq[c] * invN - mean * mean;
    float scv = gamma[c] * rsqrtf(var + BN_EPS);
    s_sc[threadIdx.x] = scv;
    s_sh[threadIdx.x] = beta[c] - mean * scv;
  }
  __syncthreads();
  int n = (blockIdx.x * 256 + threadIdx.x) >> 6;
  int lane = threadIdx.x & 63;
  if (n >= N) return;
  float2 sc = *(const float2*)&s_sc[lane * 2];
  float2 sh = *(const float2*)&s_sh[lane * 2];
  float di = dinv[n];
  float self = di * di;
  float ax0 = 0.f, ay0 = 0.f, ax1 = 0.f, ay1 = 0.f;
  float ax2 = 0.f, ay2 = 0.f, ax3 = 0.f, ay3 = 0.f;
  {
    unsigned int v = *((const unsigned int*)(h + (size_t)n * 256 + HALF * 128) + lane);
    acc2(v, self, sc, sh, ax0, ay0);
  }
  int e0 = offs[n], e1 = offs[n + 1];
  for (int eb = e0; eb < e1; eb += 64) {
    int k = min(64, e1 - eb);
    int2 me = make_int2(0, 0);
    if (lane < k) me = csr[eb + lane];
    int i = 0;
    for (; i + 8 <= k; i += 8) {
      int s0 = __shfl(me.x, i),     s1 = __shfl(me.x, i + 1);
      int s2 = __shfl(me.x, i + 2), s3 = __shfl(me.x, i + 3);
      int s4 = __shfl(me.x, i + 4), s5 = __shfl(me.x, i + 5);
      int s6 = __shfl(me.x, i + 6), s7 = __shfl(me.x, i + 7);
      float c0 = __int_as_float(__shfl(me.y, i));
      float c1 = __int_as_float(__shfl(me.y, i + 1));
      float c2 = __int_as_float(__shfl(me.y, i + 2));
      float c3 = __int_as_float(__shfl(me.y, i + 3));
      float c4 = __int_as_float(__shfl(me.y, i + 4));
      float c5 = __int_as_float(__shfl(me.y, i + 5));
      float c6 = __int_as_float(__shfl(me.y, i + 6));
      float c7 = __int_as_float(__shfl(me.y, i + 7));
      unsigned int v0 = *((const unsigned int*)(h + (size_t)s0 * 256 + HALF * 128) + lane);
      unsigned int v1 = *((const unsigned int*)(h + (size_t)s1 * 256 + HALF * 128) + lane);
      unsigned int v2 = *((const unsigned int*)(h + (size_t)s2 * 256 + HALF * 128) + lane);
      unsigned int v3 = *((const unsigned int*)(h + (size_t)s3 * 256 + HALF * 128) + lane);
      unsigned int v4 = *((const unsigned int*)(h + (size_t)s4 * 256 + HALF * 128) + lane);
      unsigned int v5 = *((const unsigned int*)(h + (size_t)s5 * 256 + HALF * 128) + lane);
      unsigned int v6 = *((const unsigned int*)(h + (size_t)s6 * 256 + HALF * 128) + lane);
      unsigned int v7 = *((const unsigned int*)(h + (size_t)s7 * 256 + HALF * 128) + lane);
      acc2(v0, c0, sc, sh, ax0, ay0);
      acc2(v1, c1, sc, sh, ax1, ay1);
      acc2(v2, c2, sc, sh, ax2, ay2);
      acc2(v3, c3, sc, sh, ax3, ay3);
      acc2(v4, c4, sc, sh, ax0, ay0);
      acc2(v5, c5, sc, sh, ax1, ay1);
      acc2(v6, c6, sc, sh, ax2, ay2);
      acc2(v7, c7, sc, sh, ax3, ay3);
    }
    for (; i + 4 <= k; i += 4) {
      int s0 = __shfl(me.x, i),     s1 = __shfl(me.x, i + 1);
      int s2 = __shfl(me.x, i + 2), s3 = __shfl(me.x, i + 3);
      float c0 = __int_as_float(__shfl(me.y, i));
      float c1 = __int_as_float(__shfl(me.y, i + 1));
      float c2 = __int_as_float(__shfl(me.y, i + 2));
      float c3 = __int_as_float(__shfl(me.y, i + 3));
      unsigned int v0 = *((const unsigned int*)(h + (size_t)s0 * 256 + HALF * 128) + lane);
      unsigned int v1 = *((const unsigned int*)(h + (size_t)s1 * 256 + HALF * 128) + lane);
      unsigned int v2 = *((const unsigned int*)(h + (size_t)s2 * 256 + HALF * 128) + lane);
      unsigned int v3 = *((const unsigned int*)(h + (size_t)s3 * 256 + HALF * 128) + lane);
      acc2(v0, c0, sc, sh, ax0, ay0);
      acc2(v1, c1, sc, sh, ax1, ay1);
      acc2(v2, c2, sc, sh, ax2, ay2);
      acc2(v3, c3, sc, sh, ax3, ay3);
    }
    for (; i < k; ++i) {
      int s = __shfl(me.x, i);
      float co = __int_as_float(__shfl(me.y, i));
      unsigned int v = *((const unsigned int*)(h + (size_t)s * 256 + HALF * 128) + lane);
      acc2(v, co, sc, sh, ax0, ay0);
    }
  }
  float ax = (ax0 + ax1) + (ax2 + ax3), ay = (ay0 + ay1) + (ay2 + ay3);
  *((unsigned int*)(out + (size_t)n * 256 + HALF * 128) + lane) =
      (unsigned int)f2bf(ax) | ((unsigned int)f2bf(ay) << 16);
}

__device__ __forceinline__ void acc128(unsigned int v, float co, float& ax, float& ay) {
  ax += co * bf2f((unsigned short)(v & 0xffff));
  ay += co * bf2f((unsigned short)(v >> 16));
}

__global__ __launch_bounds__(256) void agg128_bf(const unsigned short* __restrict__ h,
                                                 const int* __restrict__ offs,
                                                 const int2* __restrict__ csr,
                                                 const float* __restrict__ dinv,
                                                 unsigned short* __restrict__ out, int N) {
  int n = (blockIdx.x * 256 + threadIdx.x) >> 6;
  int lane = threadIdx.x & 63;
  if (n >= N) return;
  float di = dinv[n];
  float self = di * di;
  float ax0 = 0.f, ay0 = 0.f, ax1 = 0.f, ay1 = 0.f;
  float ax2 = 0.f, ay2 = 0.f, ax3 = 0.f, ay3 = 0.f;
  {
    unsigned int v = *((const unsigned int*)(h + (size_t)n * 128) + lane);
    acc128(v, self, ax0, ay0);
  }
  int e0 = offs[n], e1 = offs[n + 1];
  for (int eb = e0; eb < e1; eb += 64) {
    int k = min(64, e1 - eb);
    int2 me = make_int2(0, 0);
    if (lane < k) me = csr[eb + lane];
    int i = 0;
    for (; i + 8 <= k; i += 8) {
      int s0 = __shfl(me.x, i),     s1 = __shfl(me.x, i + 1);
      int s2 = __shfl(me.x, i + 2), s3 = __shfl(me.x, i + 3);
      int s4 = __shfl(me.x, i + 4), s5 = __shfl(me.x, i + 5);
      int s6 = __shfl(me.x, i + 6), s7 = __shfl(me.x, i + 7);
      float c0 = __int_as_float(__shfl(me.y, i));
      float c1 = __int_as_float(__shfl(me.y, i + 1));
      float c2 = __int_as_float(__shfl(me.y, i + 2));
      float c3 = __int_as_float(__shfl(me.y, i + 3));
      float c4 = __int_as_float(__shfl(me.y, i + 4));
      float c5 = __int_as_float(__shfl(me.y, i + 5));
      float c6 = __int_as_float(__shfl(me.y, i + 6));
      float c7 = __int_as_float(__shfl(me.y, i + 7));
      unsigned int v0 = *((const unsigned int*)(h + (size_t)s0 * 128) + lane);
      unsigned int v1 = *((const unsigned int*)(h + (size_t)s1 * 128) + lane);
      unsigned int v2 = *((const unsigned int*)(h + (size_t)s2 * 128) + lane);
      unsigned int v3 = *((const unsigned int*)(h + (size_t)s3 * 128) + lane);
      unsigned int v4 = *((const unsigned int*)(h + (size_t)s4 * 128) + lane);
      unsigned int v5 = *((const unsigned int*)(h + (size_t)s5 * 128) + lane);
      unsigned int v6 = *((const unsigned int*)(h + (size_t)s6 * 128) + lane);
      unsigned int v7 = *((const unsigned int*)(h + (size_t)s7 * 128) + lane);
      acc128(v0, c0, ax0, ay0); acc128(v1, c1, ax1, ay1);
      acc128(v2, c2, ax2, ay2); acc128(v3, c3, ax3, ay3);
      acc128(v4, c4, ax0, ay0); acc128(v5, c5, ax1, ay1);
      acc128(v6, c6, ax2, ay2); acc128(v7, c7, ax3, ay3);
    }
    for (; i + 4 <= k; i += 4) {
      int s0 = __shfl(me.x, i),     s1 = __shfl(me.x, i + 1);
      int s2 = __shfl(me.x, i + 2), s3 = __shfl(me.x, i + 3);
      float c0 = __int_as_float(__shfl(me.y, i));
      float c1 = __int_as_float(__shfl(me.y, i + 1));
      float c2 = __int_as_float(__shfl(me.y, i + 2));
      float c3 = __int_as_float(__shfl(me.y, i + 3));
      unsigned int v0 = *((const unsigned int*)(h + (size_t)s0 * 128) + lane);
      unsigned int v1 = *((const unsigned int*)(h + (size_t)s1 * 128) + lane);
      unsigned int v2 = *((const unsigned int*)(h + (size_t)s2 * 128) + lane);
      unsigned int v3 = *((const unsigned int*)(h + (size_t)s3 * 128) + lane);
      acc128(v0, c0, ax0, ay0); acc128(v1, c1, ax1, ay1);
      acc128(v2, c2, ax2, ay2); acc128(v3, c3, ax3, ay3);
    }
    for (; i < k; ++i) {
      int s = __shfl(me.x, i);
      float co = __int_as_float(__shfl(me.y, i));
      unsigned int v = *((const unsigned int*)(h + (size_t)s * 128) + lane);
      acc128(v, co, ax0, ay0);
    }
  }
  float ax = (ax0 + ax1) + (ax2 + ax3), ay = (ay0 + ay1) + (ay2 + ay3);
  *((unsigned int*)(out + (size_t)n * 128) + lane) =
      (unsigned int)f2bf(ax) | ((unsigned int)f2bf(ay) << 16);
}

// ---------------- bf16 MFMA GEMM + fused BN partial stats ----------------
// C[Mpad,256] = A[Mpad,K] @ W[K,256]; FULL-WIDTH tile 128x256, BK=64,
// 512 threads = 8 waves in 2 (row) x 4 (col) quadrants of 64x64 each.
// global_load_lds staging with XOR-pre-swizzled source + swizzled reads.
// Pad rows are zero -> no guards, exact-zero contribution to stats.

__global__ __launch_bounds__(512) void gemm_bf(const unsigned short* __restrict__ A,
                                               const unsigned short* __restrict__ Wt,
                                               unsigned short* __restrict__ C,
                                               int K,
                                               float* __restrict__ sums,
                                               float* __restrict__ sumsq) {
  __shared__ unsigned short As[128 * 64];   // 16 KB
  __shared__ unsigned short Bs[256 * 64];   // 32 KB
  int t = threadIdx.x;
  int w = t >> 6, lane = t & 63;
  int l16 = lane & 15, lhi = lane >> 4;
  int wr = w >> 2, wc = w & 3;              // 2x4 quadrants, each 64 rows x 64 cols
  int rowBase = blockIdx.x * 128;
  f32x4 acc[4][4] = {};
  int srow = lane >> 3;   // 0..7 within 8-row segment
  int sg = lane & 7;      // 16B group within 128B row
  const unsigned short* Abase = A + (size_t)rowBase * K;
  for (int k0 = 0; k0 < K; k0 += 64) {
#pragma unroll
    for (int r2 = 0; r2 < 2; ++r2) {
      int rb = r2 * 64 + w * 8;
      int row = rb + srow;
      int gg = sg ^ (row & 7);
      gload16(Abase + (size_t)row * K + k0 + gg * 8, &As[rb * 64]);
    }
#pragma unroll
    for (int r4 = 0; r4 < 4; ++r4) {
      int rb = r4 * 64 + w * 8;
      int row = rb + srow;
      int gg = sg ^ (row & 7);
      gload16(Wt + (size_t)row * K + k0 + gg * 8, &Bs[rb * 64]);
    }
    __syncthreads();
#pragma unroll
    for (int kk = 0; kk < 64; kk += 32) {
      int gb = (kk >> 3) + lhi;
      bf16x8 a[4], b[4];
#pragma unroll
      for (int i = 0; i < 4; ++i) {
        int ra = wr * 64 + i * 16 + l16;
        a[i] = *(const bf16x8*)&As[ra * 64 + ((gb ^ (ra & 7)) << 3)];
        int rb2 = wc * 64 + i * 16 + l16;
        b[i] = *(const bf16x8*)&Bs[rb2 * 64 + ((gb ^ (rb2 & 7)) << 3)];
      }
#pragma unroll
      for (int i = 0; i < 4; ++i)
#pragma unroll
        for (int j = 0; j < 4; ++j)
          acc[i][j] = __builtin_amdgcn_mfma_f32_16x16x32_bf16(a[i], b[j], acc[i][j], 0, 0, 0);
    }
    __syncthreads();
  }
#pragma unroll
  for (int i = 0; i < 4; ++i) {
#pragma unroll
    for (int rr = 0; rr < 4; ++rr) {
      int row = rowBase + wr * 64 + i * 16 + lhi * 4 + rr;
      size_t o = (size_t)row * 256 + wc * 64 + l16;
#pragma unroll
      for (int j = 0; j < 4; ++j) C[o + j * 16] = f2bf(acc[i][j][rr]);
    }
  }
#pragma unroll
  for (int j = 0; j < 4; ++j) {
    float s = 0.f, s2 = 0.f;
#pragma unroll
    for (int i = 0; i < 4; ++i)
#pragma unroll
      for (int rr = 0; rr < 4; ++rr) { float v = acc[i][j][rr]; s += v; s2 += v * v; }
    s  += __shfl_xor(s, 16);  s  += __shfl_xor(s, 32);
    s2 += __shfl_xor(s2, 16); s2 += __shfl_xor(s2, 32);
    if (lhi == 0) {
      int col = wc * 64 + j * 16 + l16;
      atomicAdd(&sums[col], s);
      atomicAdd(&sumsq[col], s2);
    }
  }
}

// ---------------- pool (BN2+ReLU fused, in-block finalize) + classifier ----------------

__global__ __launch_bounds__(256) void pool_final(const unsigned short* __restrict__ h,
                                                  const unsigned int* __restrict__ gstart,
                                                  const float* __restrict__ sums,
                                                  const float* __restrict__ sumsq,
                                                  const float* __restrict__ gamma,
                                                  const float* __restrict__ beta,
                                                  float invN,
                                                  const float* __restrict__ Wl,
                                                  const float* __restrict__ bl,
                                                  float* __restrict__ out, int NC) {
  __shared__ float s_sc[256], s_sh[256];
  __shared__ float4 part[4][64];
  __shared__ float p[256];
  int t = threadIdx.x, w = t >> 6, lane = t & 63;
  {
    float mean = sums[t] * invN;
    float var = sumsq[t] * invN - mean * mean;
    float scv = gamma[t] * rsqrtf(var + BN_EPS);
    s_sc[t] = scv;
    s_sh[t] = beta[t] - mean * scv;
  }
  __syncthreads();
  float4 sc = *(const float4*)&s_sc[lane * 4];
  float4 sh = *(const float4*)&s_sh[lane * 4];
  int g = blockIdx.x;
  int gs = (int)gstart[g], ge = (int)gstart[g + 1];
  float ax = 0.f, ay = 0.f, az = 0.f, aw = 0.f;
  for (int r = gs + w; r < ge; r += 4) {
    uint2 v = *((const uint2*)(h + (size_t)r * 256) + lane);
    ax += fmaxf(bf2f((unsigned short)(v.x & 0xffff)) * sc.x + sh.x, 0.f);
    ay += fmaxf(bf2f((unsigned short)(v.x >> 16)) * sc.y + sh.y, 0.f);
    az += fmaxf(bf2f((unsigned short)(v.y & 0xffff)) * sc.z + sh.z, 0.f);
    aw += fmaxf(bf2f((unsigned short)(v.y >> 16)) * sc.w + sh.w, 0.f);
  }
  part[w][lane] = make_float4(ax, ay, az, aw);
  __syncthreads();
  if (t < 64) {
    float inv = 1.0f / fmaxf((float)(ge - gs), 1.0f);
    float4 s0 = part[0][t], s1 = part[1][t], s2 = part[2][t], s3 = part[3][t];
    float4 r;
    r.x = (s0.x + s1.x + s2.x + s3.x) * inv;
    r.y = (s0.y + s1.y + s2.y + s3.y) * inv;
    r.z = (s0.z + s1.z + s2.z + s3.z) * inv;
    r.w = (s0.w + s1.w + s2.w + s3.w) * inv;
    *(float4*)&p[t * 4] = r;
  }
  __syncthreads();
  if (t < NC) {
    float s = bl[t];
    for (int k = 0; k < 256; ++k) s += p[k] * Wl[k * NC + t];
    out[g * NC + t] = s;
  }
}

// ---------------- launcher ----------------

extern "C" void kernel_launch(void* const* d_in, const int* in_sizes, int n_in,
                              void* d_out, int out_size, void* d_ws, size_t ws_size,
                              hipStream_t stream) {
  const float* x      = (const float*)d_in[0];
  const int*   ei     = (const int*)d_in[1];
  const int*   batch  = (const int*)d_in[2];
  const float* W0     = (const float*)d_in[3];
  const float* gamma0 = (const float*)d_in[5];
  const float* beta0  = (const float*)d_in[6];
  const float* W1     = (const float*)d_in[7];
  const float* gamma1 = (const float*)d_in[9];
  const float* beta1  = (const float*)d_in[10];
  const float* W2     = (const float*)d_in[11];
  const float* gamma2 = (const float*)d_in[13];
  const float* beta2  = (const float*)d_in[14];
  const float* Wl     = (const float*)d_in[15];
  const float* bl     = (const float*)d_in[16];
  float* out = (float*)d_out;

  int N = in_sizes[0] / 128;  // 50000
  int E = in_sizes[1] / 2;    // 800000
  int G = 128;
  int NC = 40;
  int Mpad = ((N + 127) / 128) * 128;  // 50048
  float invN = 1.0f / (float)N;
  const int* src = ei;
  const int* dst = ei + E;

  char* p = (char*)d_ws;
  auto alloc = [&](size_t bytes) -> void* {
    void* r = (void*)p;
    p += (bytes + 255) & ~(size_t)255;
    return r;
  };
  unsigned short* xb  = (unsigned short*)alloc((size_t)N * 128 * 2);
  unsigned short* hA  = (unsigned short*)alloc((size_t)Mpad * 256 * 2);
  unsigned short* hB  = (unsigned short*)alloc((size_t)Mpad * 256 * 2);
  unsigned short* Wt0 = (unsigned short*)alloc((size_t)256 * 128 * 2);
  unsigned short* Wt1 = (unsigned short*)alloc((size_t)256 * 256 * 2);
  unsigned short* Wt2 = (unsigned short*)alloc((size_t)256 * 256 * 2);
  int2*  csr      = (int2*) alloc((size_t)E * 8);
  int*   cc       = (int*)  alloc((size_t)(2 * N + 6 * 256) * 4);
  int*   counts   = cc;
  int*   cursor   = cc + N;
  float* stats    = (float*)(cc + 2 * N);
  float* sums0 = stats + 0 * 256, *sumsq0 = stats + 1 * 256;
  float* sums1 = stats + 2 * 256, *sumsq1 = stats + 3 * 256;
  float* sums2 = stats + 4 * 256, *sumsq2 = stats + 5 * 256;
  int*   offs     = (int*)  alloc((size_t)(N + 1) * 4);
  float* dinv     = (float*)alloc((size_t)N * 4);
  int*   blkSum   = (int*)  alloc(64 * 4);
  int*   blkOff   = (int*)  alloc(64 * 4);
  unsigned int* gstart = (unsigned int*)alloc((size_t)(G + 1) * 4);

  // ---- init ----
  hipMemsetAsync(cc, 0, (size_t)(2 * N + 6 * 256) * 4, stream);
  hipMemsetAsync(gstart, 0xFF, (size_t)(G + 1) * 4, stream);

  // ---- graph structure ----
  count_boundary<<<(E + 255) / 256, 256, 0, stream>>>(dst, E, counts, batch, N, gstart);
  int nb = (N + 1023) / 1024;
  scan1<<<nb, 256, 0, stream>>>(counts, N, offs, blkSum, dinv);
  scan2_fix<<<1, 64, 0, stream>>>(blkSum, nb, blkOff, offs, N, gstart, G);
  scan3<<<nb, 1024, 0, stream>>>(offs, N, blkOff);

  // ---- fill CSR + conversions + pad zeroing ----
  {
    int nx4 = N * 32;
    int npad128_8 = (Mpad - N) * 128 / 8;
    int npad256_8 = (Mpad - N) * 256 / 8;
    long long total = (long long)E + nx4 + 128 * 256 + 256 * 256 + 256 * 256
                    + npad128_8 + npad256_8;
    int blocks = (int)((total + 255) / 256);
    fill_cvt<<<blocks, 256, 0, stream>>>(src, dst, E, offs, cursor, dinv, csr,
                                         x, xb, nx4, W0, Wt0, W1, Wt1, W2, Wt2,
                                         hA + (size_t)N * 128, npad128_8,
                                         hA + (size_t)N * 256, npad256_8);
  }

  int aggBlocks = (N + 3) / 4;
  int gemmBlocks = Mpad / 128;  // 391

  // ---- layer 0 ----
  agg128_bf<<<aggBlocks, 256, 0, stream>>>(xb, offs, csr, dinv, hA, N);
  gemm_bf<<<gemmBlocks, 512, 0, stream>>>(hA, Wt0, hB, 128, sums0, sumsq0);

  // ---- layer 1 (BN0 finalize + ReLU fused; gather in two half-channel passes) ----
  agg256_half<0><<<aggBlocks, 256, 0, stream>>>(hB, offs, csr, dinv, sums0, sumsq0,
                                                gamma0, beta0, invN, hA, N);
  agg256_half<1><<<aggBlocks, 256, 0, stream>>>(hB, offs, csr, dinv, sums0, sumsq0,
                                                gamma0, beta0, invN, hA, N);
  gemm_bf<<<gemmBlocks, 512, 0, stream>>>(hA, Wt1, hB, 256, sums1, sumsq1);

  // ---- layer 2 ----
  agg256_half<0><<<aggBlocks, 256, 0, stream>>>(hB, offs, csr, dinv, sums1, sumsq1,
                                                gamma1, beta1, invN, hA, N);
  agg256_half<1><<<aggBlocks, 256, 0, stream>>>(hB, offs, csr, dinv, sums1, sumsq1,
                                                gamma1, beta1, invN, hA, N);
  gemm_bf<<<gemmBlocks, 512, 0, stream>>>(hA, Wt2, hB, 256, sums2, sumsq2);

  // ---- pool (BN2 finalize in-block) + classifier ----
  pool_final<<<G, 256, 0, stream>>>(hB, gstart, sums2, sumsq2, gamma2, beta2, invN,
                                    Wl, bl, out, NC);
}

// Round 13
// 483.357 us; speedup vs baseline: 1.0056x; 1.0056x over previous
//
#include <hip/hip_runtime.h>

#define BN_EPS 1e-5f

typedef __attribute__((ext_vector_type(8))) short bf16x8;
typedef __attribute__((ext_vector_type(4))) float f32x4;

__device__ __forceinline__ float bf2f(unsigned short u) {
  return __uint_as_float(((unsigned int)u) << 16);
}
__device__ __forceinline__ unsigned short f2bf(float f) {
  unsigned int u = __float_as_uint(f);
  u = u + 0x7FFFu + ((u >> 16) & 1u);   // round-to-nearest-even
  return (unsigned short)(u >> 16);
}

// async global->LDS, 16B per lane; LDS dest = (wave-uniform base) + lane*16
__device__ __forceinline__ void gload16(const unsigned short* g, unsigned short* l) {
  __builtin_amdgcn_global_load_lds(
      (const __attribute__((address_space(1))) unsigned int*)g,
      (__attribute__((address_space(3))) unsigned int*)l, 16, 0, 0);
}

// ---------------- graph structure ----------------

__global__ __launch_bounds__(256) void count_boundary(const int* __restrict__ dst, int E,
                                                      int* __restrict__ counts,
                                                      const int* __restrict__ batch, int N,
                                                      unsigned int* __restrict__ gstart) {
  int e = blockIdx.x * 256 + threadIdx.x;
  if (e < E) atomicAdd(&counts[dst[e]], 1);
  if (e < N) {
    if (e == 0 || batch[e] != batch[e - 1]) atomicMin(&gstart[batch[e]], (unsigned int)e);
  }
}

__global__ __launch_bounds__(256) void scan1(const int* __restrict__ counts, int N,
                                             int* __restrict__ offs, int* __restrict__ blkSum,
                                             float* __restrict__ dinv) {
  __shared__ int sd[256];
  int t = threadIdx.x;
  int i0 = blockIdx.x * 1024 + t * 4;
  int v0 = (i0 + 0 < N) ? counts[i0 + 0] : 0;
  int v1 = (i0 + 1 < N) ? counts[i0 + 1] : 0;
  int v2 = (i0 + 2 < N) ? counts[i0 + 2] : 0;
  int v3 = (i0 + 3 < N) ? counts[i0 + 3] : 0;
  if (i0 + 0 < N) dinv[i0 + 0] = rsqrtf((float)(v0 + 1));
  if (i0 + 1 < N) dinv[i0 + 1] = rsqrtf((float)(v1 + 1));
  if (i0 + 2 < N) dinv[i0 + 2] = rsqrtf((float)(v2 + 1));
  if (i0 + 3 < N) dinv[i0 + 3] = rsqrtf((float)(v3 + 1));
  int tot = v0 + v1 + v2 + v3;
  sd[t] = tot;
  __syncthreads();
  for (int off = 1; off < 256; off <<= 1) {
    int x = (t >= off) ? sd[t - off] : 0;
    __syncthreads();
    sd[t] += x;
    __syncthreads();
  }
  int excl = sd[t] - tot;
  if (i0 + 0 < N) offs[i0 + 0] = excl;
  if (i0 + 1 < N) offs[i0 + 1] = excl + v0;
  if (i0 + 2 < N) offs[i0 + 2] = excl + v0 + v1;
  if (i0 + 3 < N) offs[i0 + 3] = excl + v0 + v1 + v2;
  if (t == 255) blkSum[blockIdx.x] = sd[255];
}

__global__ void scan2_fix(const int* __restrict__ blkSum, int nb, int* __restrict__ blkOff,
                          int* __restrict__ offs, int N,
                          unsigned int* __restrict__ gstart, int G) {
  if (blockIdx.x != 0) return;
  if (threadIdx.x == 0) {
    int run = 0;
    for (int b = 0; b < nb; ++b) { blkOff[b] = run; run += blkSum[b]; }
    offs[N] = run;
  } else if (threadIdx.x == 1) {
    gstart[G] = (unsigned int)N;
    for (int g = G - 1; g >= 0; --g)
      if (gstart[g] == 0xFFFFFFFFu) gstart[g] = gstart[g + 1];
  }
}

__global__ __launch_bounds__(1024) void scan3(int* __restrict__ offs, int N,
                                              const int* __restrict__ blkOff) {
  int i = blockIdx.x * 1024 + threadIdx.x;
  if (i < N) offs[i] += blkOff[blockIdx.x];
}

// ---------------- fill CSR (4B src-only) + dtype conversions + pad zeroing ----------------
// csr entry is just the src index (4B): halves the random-scatter dirty-line
// footprint vs (src,coef) 8B. coef = dinv[src]*dinv[dst] is recomputed in the
// agg kernels from the L2-resident dinv table (same f32 product, bit-identical).

__global__ __launch_bounds__(256) void fill_cvt(const int* __restrict__ src,
                                                const int* __restrict__ dst, int E,
                                                const int* __restrict__ offs,
                                                int* __restrict__ cursor,
                                                int* __restrict__ csr_src,
                                                const float* __restrict__ x,
                                                unsigned short* __restrict__ xb, int nx4,
                                                const float* __restrict__ W0,
                                                unsigned short* __restrict__ Wt0,
                                                const float* __restrict__ W1,
                                                unsigned short* __restrict__ Wt1,
                                                const float* __restrict__ W2,
                                                unsigned short* __restrict__ Wt2,
                                                unsigned short* __restrict__ pad128, int npad128_8,
                                                unsigned short* __restrict__ pad256, int npad256_8) {
  long long idx = (long long)blockIdx.x * 256 + threadIdx.x;
  if (idx < E) {
    int e = (int)idx;
    int s = src[e], d = dst[e];
    int pos = offs[d] + atomicAdd(&cursor[d], 1);
    csr_src[pos] = s;
    return;
  }
  idx -= E;
  if (idx < nx4) {
    float4 v = ((const float4*)x)[idx];
    unsigned int lo = (unsigned int)f2bf(v.x) | ((unsigned int)f2bf(v.y) << 16);
    unsigned int hi = (unsigned int)f2bf(v.z) | ((unsigned int)f2bf(v.w) << 16);
    ((uint2*)xb)[idx] = make_uint2(lo, hi);
    return;
  }
  idx -= nx4;
  if (idx < 128 * 256) {
    int k = (int)(idx >> 8), n = (int)(idx & 255);
    Wt0[n * 128 + k] = f2bf(W0[k * 256 + n]);
    return;
  }
  idx -= 128 * 256;
  if (idx < 256 * 256) {
    int k = (int)(idx >> 8), n = (int)(idx & 255);
    Wt1[n * 256 + k] = f2bf(W1[k * 256 + n]);
    return;
  }
  idx -= 256 * 256;
  if (idx < 256 * 256) {
    int k = (int)(idx >> 8), n = (int)(idx & 255);
    Wt2[n * 256 + k] = f2bf(W2[k * 256 + n]);
    return;
  }
  idx -= 256 * 256;
  if (idx < npad128_8) { ((uint4*)pad128)[idx] = make_uint4(0, 0, 0, 0); return; }
  idx -= npad128_8;
  if (idx < npad256_8) { ((uint4*)pad256)[idx] = make_uint4(0, 0, 0, 0); return; }
}

// ---------------- aggregation (gather, CSR by dst), one wave per node ----------------
// 8-edge unroll, 4 accumulator chains; BN scale/shift of the previous layer is
// computed in an LDS prologue and applied per gathered row (fused, R11-style).
// coef = dinv[src]*dinv[dst]: lane gathers dinv[src] alongside the src index.

__device__ __forceinline__ void acc256(uint2 v, float co, float4 sc, float4 sh,
                                       float& ax, float& ay, float& az, float& aw) {
  float fx = fmaxf(bf2f((unsigned short)(v.x & 0xffff)) * sc.x + sh.x, 0.f);
  float fy = fmaxf(bf2f((unsigned short)(v.x >> 16)) * sc.y + sh.y, 0.f);
  float fz = fmaxf(bf2f((unsigned short)(v.y & 0xffff)) * sc.z + sh.z, 0.f);
  float fw = fmaxf(bf2f((unsigned short)(v.y >> 16)) * sc.w + sh.w, 0.f);
  ax += co * fx; ay += co * fy; az += co * fz; aw += co * fw;
}

__global__ __launch_bounds__(256) void agg256_bf(const unsigned short* __restrict__ h,
                                                 const int* __restrict__ offs,
                                                 const int* __restrict__ csr_src,
                                                 const float* __restrict__ dinv,
                                                 const float* __restrict__ sums,
                                                 const float* __restrict__ sumsq,
                                                 const float* __restrict__ gamma,
                                                 const float* __restrict__ beta,
                                                 float invN,
                                                 unsigned short* __restrict__ out, int N) {
  __shared__ float s_sc[256], s_sh[256];
  {
    int c = threadIdx.x;
    float mean = sums[c] * invN;
    float var = sumsq[c] * invN - mean * mean;
    float scv = gamma[c] * rsqrtf(var + BN_EPS);
    s_sc[c] = scv;
    s_sh[c] = beta[c] - mean * scv;
  }
  __syncthreads();
  int n = (blockIdx.x * 256 + threadIdx.x) >> 6;
  int lane = threadIdx.x & 63;
  if (n >= N) return;
  float4 sc = *(const float4*)&s_sc[lane * 4];
  float4 sh = *(const float4*)&s_sh[lane * 4];
  float di = dinv[n];
  float self = di * di;
  float ax0 = 0.f, ay0 = 0.f, az0 = 0.f, aw0 = 0.f;
  float ax1 = 0.f, ay1 = 0.f, az1 = 0.f, aw1 = 0.f;
  float ax2 = 0.f, ay2 = 0.f, az2 = 0.f, aw2 = 0.f;
  float ax3 = 0.f, ay3 = 0.f, az3 = 0.f, aw3 = 0.f;
  {
    uint2 v = *((const uint2*)(h + (size_t)n * 256) + lane);
    acc256(v, self, sc, sh, ax0, ay0, az0, aw0);
  }
  int e0 = offs[n], e1 = offs[n + 1];
  for (int eb = e0; eb < e1; eb += 64) {
    int k = min(64, e1 - eb);
    int sv = 0; float dv = 0.f;
    if (lane < k) { sv = csr_src[eb + lane]; dv = dinv[sv]; }
    int i = 0;
    for (; i + 8 <= k; i += 8) {
      int s0 = __shfl(sv, i),     s1 = __shfl(sv, i + 1);
      int s2 = __shfl(sv, i + 2), s3 = __shfl(sv, i + 3);
      int s4 = __shfl(sv, i + 4), s5 = __shfl(sv, i + 5);
      int s6 = __shfl(sv, i + 6), s7 = __shfl(sv, i + 7);
      float c0 = __shfl(dv, i) * di,     c1 = __shfl(dv, i + 1) * di;
      float c2 = __shfl(dv, i + 2) * di, c3 = __shfl(dv, i + 3) * di;
      float c4 = __shfl(dv, i + 4) * di, c5 = __shfl(dv, i + 5) * di;
      float c6 = __shfl(dv, i + 6) * di, c7 = __shfl(dv, i + 7) * di;
      uint2 v0 = *((const uint2*)(h + (size_t)s0 * 256) + lane);
      uint2 v1 = *((const uint2*)(h + (size_t)s1 * 256) + lane);
      uint2 v2 = *((const uint2*)(h + (size_t)s2 * 256) + lane);
      uint2 v3 = *((const uint2*)(h + (size_t)s3 * 256) + lane);
      uint2 v4 = *((const uint2*)(h + (size_t)s4 * 256) + lane);
      uint2 v5 = *((const uint2*)(h + (size_t)s5 * 256) + lane);
      uint2 v6 = *((const uint2*)(h + (size_t)s6 * 256) + lane);
      uint2 v7 = *((const uint2*)(h + (size_t)s7 * 256) + lane);
      acc256(v0, c0, sc, sh, ax0, ay0, az0, aw0);
      acc256(v1, c1, sc, sh, ax1, ay1, az1, aw1);
      acc256(v2, c2, sc, sh, ax2, ay2, az2, aw2);
      acc256(v3, c3, sc, sh, ax3, ay3, az3, aw3);
      acc256(v4, c4, sc, sh, ax0, ay0, az0, aw0);
      acc256(v5, c5, sc, sh, ax1, ay1, az1, aw1);
      acc256(v6, c6, sc, sh, ax2, ay2, az2, aw2);
      acc256(v7, c7, sc, sh, ax3, ay3, az3, aw3);
    }
    for (; i + 4 <= k; i += 4) {
      int s0 = __shfl(sv, i),     s1 = __shfl(sv, i + 1);
      int s2 = __shfl(sv, i + 2), s3 = __shfl(sv, i + 3);
      float c0 = __shfl(dv, i) * di,     c1 = __shfl(dv, i + 1) * di;
      float c2 = __shfl(dv, i + 2) * di, c3 = __shfl(dv, i + 3) * di;
      uint2 v0 = *((const uint2*)(h + (size_t)s0 * 256) + lane);
      uint2 v1 = *((const uint2*)(h + (size_t)s1 * 256) + lane);
      uint2 v2 = *((const uint2*)(h + (size_t)s2 * 256) + lane);
      uint2 v3 = *((const uint2*)(h + (size_t)s3 * 256) + lane);
      acc256(v0, c0, sc, sh, ax0, ay0, az0, aw0);
      acc256(v1, c1, sc, sh, ax1, ay1, az1, aw1);
      acc256(v2, c2, sc, sh, ax2, ay2, az2, aw2);
      acc256(v3, c3, sc, sh, ax3, ay3, az3, aw3);
    }
    for (; i < k; ++i) {
      int s = __shfl(sv, i);
      float co = __shfl(dv, i) * di;
      uint2 v = *((const uint2*)(h + (size_t)s * 256) + lane);
      acc256(v, co, sc, sh, ax0, ay0, az0, aw0);
    }
  }
  float ax = (ax0 + ax1) + (ax2 + ax3), ay = (ay0 + ay1) + (ay2 + ay3);
  float az = (az0 + az1) + (az2 + az3), aw = (aw0 + aw1) + (aw2 + aw3);
  unsigned int lo = (unsigned int)f2bf(ax) | ((unsigned int)f2bf(ay) << 16);
  unsigned int hi = (unsigned int)f2bf(az) | ((unsigned int)f2bf(aw) << 16);
  *((uint2*)(out + (size_t)n * 256) + lane) = make_uint2(lo, hi);
}

__device__ __forceinline__ void acc128(unsigned int v, float co, float& ax, float& ay) {
  ax += co * bf2f((unsigned short)(v & 0xffff));
  ay += co * bf2f((unsigned short)(v >> 16));
}

__global__ __launch_bounds__(256) void agg128_bf(const unsigned short* __restrict__ h,
                                                 const int* __restrict__ offs,
                                                 const int* __restrict__ csr_src,
                                                 const float* __restrict__ dinv,
                                                 unsigned short* __restrict__ out, int N) {
  int n = (blockIdx.x * 256 + threadIdx.x) >> 6;
  int lane = threadIdx.x & 63;
  if (n >= N) return;
  float di = dinv[n];
  float self = di * di;
  float ax0 = 0.f, ay0 = 0.f, ax1 = 0.f, ay1 = 0.f;
  float ax2 = 0.f, ay2 = 0.f, ax3 = 0.f, ay3 = 0.f;
  {
    unsigned int v = *((const unsigned int*)(h + (size_t)n * 128) + lane);
    acc128(v, self, ax0, ay0);
  }
  int e0 = offs[n], e1 = offs[n + 1];
  for (int eb = e0; eb < e1; eb += 64) {
    int k = min(64, e1 - eb);
    int sv = 0; float dv = 0.f;
    if (lane < k) { sv = csr_src[eb + lane]; dv = dinv[sv]; }
    int i = 0;
    for (; i + 8 <= k; i += 8) {
      int s0 = __shfl(sv, i),     s1 = __shfl(sv, i + 1);
      int s2 = __shfl(sv, i + 2), s3 = __shfl(sv, i + 3);
      int s4 = __shfl(sv, i + 4), s5 = __shfl(sv, i + 5);
      int s6 = __shfl(sv, i + 6), s7 = __shfl(sv, i + 7);
      float c0 = __shfl(dv, i) * di,     c1 = __shfl(dv, i + 1) * di;
      float c2 = __shfl(dv, i + 2) * di, c3 = __shfl(dv, i + 3) * di;
      float c4 = __shfl(dv, i + 4) * di, c5 = __shfl(dv, i + 5) * di;
      float c6 = __shfl(dv, i + 6) * di, c7 = __shfl(dv, i + 7) * di;
      unsigned int v0 = *((const unsigned int*)(h + (size_t)s0 * 128) + lane);
      unsigned int v1 = *((const unsigned int*)(h + (size_t)s1 * 128) + lane);
      unsigned int v2 = *((const unsigned int*)(h + (size_t)s2 * 128) + lane);
      unsigned int v3 = *((const unsigned int*)(h + (size_t)s3 * 128) + lane);
      unsigned int v4 = *((const unsigned int*)(h + (size_t)s4 * 128) + lane);
      unsigned int v5 = *((const unsigned int*)(h + (size_t)s5 * 128) + lane);
      unsigned int v6 = *((const unsigned int*)(h + (size_t)s6 * 128) + lane);
      unsigned int v7 = *((const unsigned int*)(h + (size_t)s7 * 128) + lane);
      acc128(v0, c0, ax0, ay0); acc128(v1, c1, ax1, ay1);
      acc128(v2, c2, ax2, ay2); acc128(v3, c3, ax3, ay3);
      acc128(v4, c4, ax0, ay0); acc128(v5, c5, ax1, ay1);
      acc128(v6, c6, ax2, ay2); acc128(v7, c7, ax3, ay3);
    }
    for (; i + 4 <= k; i += 4) {
      int s0 = __shfl(sv, i),     s1 = __shfl(sv, i + 1);
      int s2 = __shfl(sv, i + 2), s3 = __shfl(sv, i + 3);
      float c0 = __shfl(dv, i) * di,     c1 = __shfl(dv, i + 1) * di;
      float c2 = __shfl(dv, i + 2) * di, c3 = __shfl(dv, i + 3) * di;
      unsigned int v0 = *((const unsigned int*)(h + (size_t)s0 * 128) + lane);
      unsigned int v1 = *((const unsigned int*)(h + (size_t)s1 * 128) + lane);
      unsigned int v2 = *((const unsigned int*)(h + (size_t)s2 * 128) + lane);
      unsigned int v3 = *((const unsigned int*)(h + (size_t)s3 * 128) + lane);
      acc128(v0, c0, ax0, ay0); acc128(v1, c1, ax1, ay1);
      acc128(v2, c2, ax2, ay2); acc128(v3, c3, ax3, ay3);
    }
    for (; i < k; ++i) {
      int s = __shfl(sv, i);
      float co = __shfl(dv, i) * di;
      unsigned int v = *((const unsigned int*)(h + (size_t)s * 128) + lane);
      acc128(v, co, ax0, ay0);
    }
  }
  float ax = (ax0 + ax1) + (ax2 + ax3), ay = (ay0 + ay1) + (ay2 + ay3);
  *((unsigned int*)(out + (size_t)n * 128) + lane) =
      (unsigned int)f2bf(ax) | ((unsigned int)f2bf(ay) << 16);
}

// ---------------- bf16 MFMA GEMM + fused BN partial stats ----------------
// C[Mpad,256] = A[Mpad,K] @ W[K,256]; FULL-WIDTH tile 128x256, BK=64,
// 512 threads = 8 waves in 2 (row) x 4 (col) quadrants of 64x64 each.
// global_load_lds staging with XOR-pre-swizzled source + swizzled reads.
// Pad rows are zero -> no guards, exact-zero contribution to stats.

__global__ __launch_bounds__(512) void gemm_bf(const unsigned short* __restrict__ A,
                                               const unsigned short* __restrict__ Wt,
                                               unsigned short* __restrict__ C,
                                               int K,
                                               float* __restrict__ sums,
                                               float* __restrict__ sumsq) {
  __shared__ unsigned short As[128 * 64];   // 16 KB
  __shared__ unsigned short Bs[256 * 64];   // 32 KB
  int t = threadIdx.x;
  int w = t >> 6, lane = t & 63;
  int l16 = lane & 15, lhi = lane >> 4;
  int wr = w >> 2, wc = w & 3;              // 2x4 quadrants, each 64 rows x 64 cols
  int rowBase = blockIdx.x * 128;
  f32x4 acc[4][4] = {};
  int srow = lane >> 3;   // 0..7 within 8-row segment
  int sg = lane & 7;      // 16B group within 128B row
  const unsigned short* Abase = A + (size_t)rowBase * K;
  for (int k0 = 0; k0 < K; k0 += 64) {
#pragma unroll
    for (int r2 = 0; r2 < 2; ++r2) {
      int rb = r2 * 64 + w * 8;
      int row = rb + srow;
      int gg = sg ^ (row & 7);
      gload16(Abase + (size_t)row * K + k0 + gg * 8, &As[rb * 64]);
    }
#pragma unroll
    for (int r4 = 0; r4 < 4; ++r4) {
      int rb = r4 * 64 + w * 8;
      int row = rb + srow;
      int gg = sg ^ (row & 7);
      gload16(Wt + (size_t)row * K + k0 + gg * 8, &Bs[rb * 64]);
    }
    __syncthreads();
#pragma unroll
    for (int kk = 0; kk < 64; kk += 32) {
      int gb = (kk >> 3) + lhi;
      bf16x8 a[4], b[4];
#pragma unroll
      for (int i = 0; i < 4; ++i) {
        int ra = wr * 64 + i * 16 + l16;
        a[i] = *(const bf16x8*)&As[ra * 64 + ((gb ^ (ra & 7)) << 3)];
        int rb2 = wc * 64 + i * 16 + l16;
        b[i] = *(const bf16x8*)&Bs[rb2 * 64 + ((gb ^ (rb2 & 7)) << 3)];
      }
#pragma unroll
      for (int i = 0; i < 4; ++i)
#pragma unroll
        for (int j = 0; j < 4; ++j)
          acc[i][j] = __builtin_amdgcn_mfma_f32_16x16x32_bf16(a[i], b[j], acc[i][j], 0, 0, 0);
    }
    __syncthreads();
  }
#pragma unroll
  for (int i = 0; i < 4; ++i) {
#pragma unroll
    for (int rr = 0; rr < 4; ++rr) {
      int row = rowBase + wr * 64 + i * 16 + lhi * 4 + rr;
      size_t o = (size_t)row * 256 + wc * 64 + l16;
#pragma unroll
      for (int j = 0; j < 4; ++j) C[o + j * 16] = f2bf(acc[i][j][rr]);
    }
  }
#pragma unroll
  for (int j = 0; j < 4; ++j) {
    float s = 0.f, s2 = 0.f;
#pragma unroll
    for (int i = 0; i < 4; ++i)
#pragma unroll
      for (int rr = 0; rr < 4; ++rr) { float v = acc[i][j][rr]; s += v; s2 += v * v; }
    s  += __shfl_xor(s, 16);  s  += __shfl_xor(s, 32);
    s2 += __shfl_xor(s2, 16); s2 += __shfl_xor(s2, 32);
    if (lhi == 0) {
      int col = wc * 64 + j * 16 + l16;
      atomicAdd(&sums[col], s);
      atomicAdd(&sumsq[col], s2);
    }
  }
}

// ---------------- pool (BN2+ReLU fused, in-block finalize) + classifier ----------------

__global__ __launch_bounds__(256) void pool_final(const unsigned short* __restrict__ h,
                                                  const unsigned int* __restrict__ gstart,
                                                  const float* __restrict__ sums,
                                                  const float* __restrict__ sumsq,
                                                  const float* __restrict__ gamma,
                                                  const float* __restrict__ beta,
                                                  float invN,
                                                  const float* __restrict__ Wl,
                                                  const float* __restrict__ bl,
                                                  float* __restrict__ out, int NC) {
  __shared__ float s_sc[256], s_sh[256];
  __shared__ float4 part[4][64];
  __shared__ float p[256];
  int t = threadIdx.x, w = t >> 6, lane = t & 63;
  {
    float mean = sums[t] * invN;
    float var = sumsq[t] * invN - mean * mean;
    float scv = gamma[t] * rsqrtf(var + BN_EPS);
    s_sc[t] = scv;
    s_sh[t] = beta[t] - mean * scv;
  }
  __syncthreads();
  float4 sc = *(const float4*)&s_sc[lane * 4];
  float4 sh = *(const float4*)&s_sh[lane * 4];
  int g = blockIdx.x;
  int gs = (int)gstart[g], ge = (int)gstart[g + 1];
  float ax = 0.f, ay = 0.f, az = 0.f, aw = 0.f;
  for (int r = gs + w; r < ge; r += 4) {
    uint2 v = *((const uint2*)(h + (size_t)r * 256) + lane);
    ax += fmaxf(bf2f((unsigned short)(v.x & 0xffff)) * sc.x + sh.x, 0.f);
    ay += fmaxf(bf2f((unsigned short)(v.x >> 16)) * sc.y + sh.y, 0.f);
    az += fmaxf(bf2f((unsigned short)(v.y & 0xffff)) * sc.z + sh.z, 0.f);
    aw += fmaxf(bf2f((unsigned short)(v.y >> 16)) * sc.w + sh.w, 0.f);
  }
  part[w][lane] = make_float4(ax, ay, az, aw);
  __syncthreads();
  if (t < 64) {
    float inv = 1.0f / fmaxf((float)(ge - gs), 1.0f);
    float4 s0 = part[0][t], s1 = part[1][t], s2 = part[2][t], s3 = part[3][t];
    float4 r;
    r.x = (s0.x + s1.x + s2.x + s3.x) * inv;
    r.y = (s0.y + s1.y + s2.y + s3.y) * inv;
    r.z = (s0.z + s1.z + s2.z + s3.z) * inv;
    r.w = (s0.w + s1.w + s2.w + s3.w) * inv;
    *(float4*)&p[t * 4] = r;
  }
  __syncthreads();
  if (t < NC) {
    float s = bl[t];
    for (int k = 0; k < 256; ++k) s += p[k] * Wl[k * NC + t];
    out[g * NC + t] = s;
  }
}

// ---------------- launcher ----------------

extern "C" void kernel_launch(void* const* d_in, const int* in_sizes, int n_in,
                              void* d_out, int out_size, void* d_ws, size_t ws_size,
                              hipStream_t stream) {
  const float* x      = (const float*)d_in[0];
  const int*   ei     = (const int*)d_in[1];
  const int*   batch  = (const int*)d_in[2];
  const float* W0     = (const float*)d_in[3];
  const float* gamma0 = (const float*)d_in[5];
  const float* beta0  = (const float*)d_in[6];
  const float* W1     = (const float*)d_in[7];
  const float* gamma1 = (const float*)d_in[9];
  const float* beta1  = (const float*)d_in[10];
  const float* W2     = (const float*)d_in[11];
  const float* gamma2 = (const float*)d_in[13];
  const float* beta2  = (const float*)d_in[14];
  const float* Wl     = (const float*)d_in[15];
  const float* bl     = (const float*)d_in[16];
  float* out = (float*)d_out;

  int N = in_sizes[0] / 128;  // 50000
  int E = in_sizes[1] / 2;    // 800000
  int G = 128;
  int NC = 40;
  int Mpad = ((N + 127) / 128) * 128;  // 50048
  float invN = 1.0f / (float)N;
  const int* src = ei;
  const int* dst = ei + E;

  char* p = (char*)d_ws;
  auto alloc = [&](size_t bytes) -> void* {
    void* r = (void*)p;
    p += (bytes + 255) & ~(size_t)255;
    return r;
  };
  unsigned short* xb  = (unsigned short*)alloc((size_t)N * 128 * 2);
  unsigned short* hA  = (unsigned short*)alloc((size_t)Mpad * 256 * 2);
  unsigned short* hB  = (unsigned short*)alloc((size_t)Mpad * 256 * 2);
  unsigned short* Wt0 = (unsigned short*)alloc((size_t)256 * 128 * 2);
  unsigned short* Wt1 = (unsigned short*)alloc((size_t)256 * 256 * 2);
  unsigned short* Wt2 = (unsigned short*)alloc((size_t)256 * 256 * 2);
  int*   csr_src  = (int*)  alloc((size_t)E * 4);
  int*   cc       = (int*)  alloc((size_t)(2 * N + 6 * 256) * 4);
  int*   counts   = cc;
  int*   cursor   = cc + N;
  float* stats    = (float*)(cc + 2 * N);
  float* sums0 = stats + 0 * 256, *sumsq0 = stats + 1 * 256;
  float* sums1 = stats + 2 * 256, *sumsq1 = stats + 3 * 256;
  float* sums2 = stats + 4 * 256, *sumsq2 = stats + 5 * 256;
  int*   offs     = (int*)  alloc((size_t)(N + 1) * 4);
  float* dinv     = (float*)alloc((size_t)N * 4);
  int*   blkSum   = (int*)  alloc(64 * 4);
  int*   blkOff   = (int*)  alloc(64 * 4);
  unsigned int* gstart = (unsigned int*)alloc((size_t)(G + 1) * 4);

  // ---- init ----
  hipMemsetAsync(cc, 0, (size_t)(2 * N + 6 * 256) * 4, stream);
  hipMemsetAsync(gstart, 0xFF, (size_t)(G + 1) * 4, stream);

  // ---- graph structure ----
  count_boundary<<<(E + 255) / 256, 256, 0, stream>>>(dst, E, counts, batch, N, gstart);
  int nb = (N + 1023) / 1024;
  scan1<<<nb, 256, 0, stream>>>(counts, N, offs, blkSum, dinv);
  scan2_fix<<<1, 64, 0, stream>>>(blkSum, nb, blkOff, offs, N, gstart, G);
  scan3<<<nb, 1024, 0, stream>>>(offs, N, blkOff);

  // ---- fill CSR + conversions + pad zeroing ----
  {
    int nx4 = N * 32;
    int npad128_8 = (Mpad - N) * 128 / 8;
    int npad256_8 = (Mpad - N) * 256 / 8;
    long long total = (long long)E + nx4 + 128 * 256 + 256 * 256 + 256 * 256
                    + npad128_8 + npad256_8;
    int blocks = (int)((total + 255) / 256);
    fill_cvt<<<blocks, 256, 0, stream>>>(src, dst, E, offs, cursor, csr_src,
                                         x, xb, nx4, W0, Wt0, W1, Wt1, W2, Wt2,
                                         hA + (size_t)N * 128, npad128_8,
                                         hA + (size_t)N * 256, npad256_8);
  }

  int aggBlocks = (N + 3) / 4;
  int gemmBlocks = Mpad / 128;  // 391

  // ---- layer 0 ----
  agg128_bf<<<aggBlocks, 256, 0, stream>>>(xb, offs, csr_src, dinv, hA, N);
  gemm_bf<<<gemmBlocks, 512, 0, stream>>>(hA, Wt0, hB, 128, sums0, sumsq0);

  // ---- layer 1 (BN0 finalize + ReLU fused into gather prologue) ----
  agg256_bf<<<aggBlocks, 256, 0, stream>>>(hB, offs, csr_src, dinv, sums0, sumsq0,
                                           gamma0, beta0, invN, hA, N);
  gemm_bf<<<gemmBlocks, 512, 0, stream>>>(hA, Wt1, hB, 256, sums1, sumsq1);

  // ---- layer 2 ----
  agg256_bf<<<aggBlocks, 256, 0, stream>>>(hB, offs, csr_src, dinv, sums1, sumsq1,
                                           gamma1, beta1, invN, hA, N);
  gemm_bf<<<gemmBlocks, 512, 0, stream>>>(hA, Wt2, hB, 256, sums2, sumsq2);

  // ---- pool (BN2 finalize in-block) + classifier ----
  pool_final<<<G, 256, 0, stream>>>(hB, gstart, sums2, sumsq2, gamma2, beta2, invN,
                                    Wl, bl, out, NC);
}

// Round 14
// 481.287 us; speedup vs baseline: 1.0099x; 1.0043x over previous
//
#include <hip/hip_runtime.h>

#define BN_EPS 1e-5f

typedef __attribute__((ext_vector_type(8))) short bf16x8;
typedef __attribute__((ext_vector_type(4))) float f32x4;

__device__ __forceinline__ float bf2f(unsigned short u) {
  return __uint_as_float(((unsigned int)u) << 16);
}
__device__ __forceinline__ unsigned short f2bf(float f) {
  unsigned int u = __float_as_uint(f);
  u = u + 0x7FFFu + ((u >> 16) & 1u);   // round-to-nearest-even
  return (unsigned short)(u >> 16);
}

// async global->LDS, 16B per lane; LDS dest = (wave-uniform base) + lane*16
__device__ __forceinline__ void gload16(const unsigned short* g, unsigned short* l) {
  __builtin_amdgcn_global_load_lds(
      (const __attribute__((address_space(1))) unsigned int*)g,
      (__attribute__((address_space(3))) unsigned int*)l, 16, 0, 0);
}

// ---------------- count+boundary + dtype conversions + pad zeroing ----------------
// The cvt/pad work has no dependency on the scan; count is atomic-latency-bound
// with idle issue slots, so the streaming cvt work rides along ~free.

__global__ __launch_bounds__(256) void count_cvt(const int* __restrict__ dst, int E,
                                                 int* __restrict__ counts,
                                                 const int* __restrict__ batch, int N,
                                                 unsigned int* __restrict__ gstart,
                                                 const float* __restrict__ x,
                                                 unsigned short* __restrict__ xb, int nx4,
                                                 const float* __restrict__ W0,
                                                 unsigned short* __restrict__ Wt0,
                                                 const float* __restrict__ W1,
                                                 unsigned short* __restrict__ Wt1,
                                                 const float* __restrict__ W2,
                                                 unsigned short* __restrict__ Wt2,
                                                 unsigned short* __restrict__ pad128, int npad128_8,
                                                 unsigned short* __restrict__ pad256, int npad256_8) {
  long long idx = (long long)blockIdx.x * 256 + threadIdx.x;
  if (idx < E) {
    int e = (int)idx;
    atomicAdd(&counts[dst[e]], 1);
    if (e < N) {
      if (e == 0 || batch[e] != batch[e - 1]) atomicMin(&gstart[batch[e]], (unsigned int)e);
    }
    return;
  }
  idx -= E;
  if (idx < nx4) {
    float4 v = ((const float4*)x)[idx];
    unsigned int lo = (unsigned int)f2bf(v.x) | ((unsigned int)f2bf(v.y) << 16);
    unsigned int hi = (unsigned int)f2bf(v.z) | ((unsigned int)f2bf(v.w) << 16);
    ((uint2*)xb)[idx] = make_uint2(lo, hi);
    return;
  }
  idx -= nx4;
  if (idx < 128 * 256) {
    int k = (int)(idx >> 8), n = (int)(idx & 255);
    Wt0[n * 128 + k] = f2bf(W0[k * 256 + n]);
    return;
  }
  idx -= 128 * 256;
  if (idx < 256 * 256) {
    int k = (int)(idx >> 8), n = (int)(idx & 255);
    Wt1[n * 256 + k] = f2bf(W1[k * 256 + n]);
    return;
  }
  idx -= 256 * 256;
  if (idx < 256 * 256) {
    int k = (int)(idx >> 8), n = (int)(idx & 255);
    Wt2[n * 256 + k] = f2bf(W2[k * 256 + n]);
    return;
  }
  idx -= 256 * 256;
  if (idx < npad128_8) { ((uint4*)pad128)[idx] = make_uint4(0, 0, 0, 0); return; }
  idx -= npad128_8;
  if (idx < npad256_8) { ((uint4*)pad256)[idx] = make_uint4(0, 0, 0, 0); return; }
}

__global__ __launch_bounds__(256) void scan1(const int* __restrict__ counts, int N,
                                             int* __restrict__ offs, int* __restrict__ blkSum,
                                             float* __restrict__ dinv) {
  __shared__ int sd[256];
  int t = threadIdx.x;
  int i0 = blockIdx.x * 1024 + t * 4;
  int v0 = (i0 + 0 < N) ? counts[i0 + 0] : 0;
  int v1 = (i0 + 1 < N) ? counts[i0 + 1] : 0;
  int v2 = (i0 + 2 < N) ? counts[i0 + 2] : 0;
  int v3 = (i0 + 3 < N) ? counts[i0 + 3] : 0;
  if (i0 + 0 < N) dinv[i0 + 0] = rsqrtf((float)(v0 + 1));
  if (i0 + 1 < N) dinv[i0 + 1] = rsqrtf((float)(v1 + 1));
  if (i0 + 2 < N) dinv[i0 + 2] = rsqrtf((float)(v2 + 1));
  if (i0 + 3 < N) dinv[i0 + 3] = rsqrtf((float)(v3 + 1));
  int tot = v0 + v1 + v2 + v3;
  sd[t] = tot;
  __syncthreads();
  for (int off = 1; off < 256; off <<= 1) {
    int x = (t >= off) ? sd[t - off] : 0;
    __syncthreads();
    sd[t] += x;
    __syncthreads();
  }
  int excl = sd[t] - tot;
  if (i0 + 0 < N) offs[i0 + 0] = excl;
  if (i0 + 1 < N) offs[i0 + 1] = excl + v0;
  if (i0 + 2 < N) offs[i0 + 2] = excl + v0 + v1;
  if (i0 + 3 < N) offs[i0 + 3] = excl + v0 + v1 + v2;
  if (t == 255) blkSum[blockIdx.x] = sd[255];
}

__global__ void scan2_fix(const int* __restrict__ blkSum, int nb, int* __restrict__ blkOff,
                          int* __restrict__ offs, int N,
                          unsigned int* __restrict__ gstart, int G) {
  if (blockIdx.x != 0) return;
  if (threadIdx.x == 0) {
    int run = 0;
    for (int b = 0; b < nb; ++b) { blkOff[b] = run; run += blkSum[b]; }
    offs[N] = run;
  } else if (threadIdx.x == 1) {
    gstart[G] = (unsigned int)N;
    for (int g = G - 1; g >= 0; --g)
      if (gstart[g] == 0xFFFFFFFFu) gstart[g] = gstart[g + 1];
  }
}

__global__ __launch_bounds__(1024) void scan3(int* __restrict__ offs, int N,
                                              const int* __restrict__ blkOff) {
  int i = blockIdx.x * 1024 + threadIdx.x;
  if (i < N) offs[i] += blkOff[blockIdx.x];
}

// ---------------- fill CSR (scatter only): (src, coef) packed 8B ----------------

__global__ __launch_bounds__(256) void fill_kernel(const int* __restrict__ src,
                                                   const int* __restrict__ dst, int E,
                                                   const int* __restrict__ offs,
                                                   int* __restrict__ cursor,
                                                   const float* __restrict__ dinv,
                                                   int2* __restrict__ csr) {
  int e = blockIdx.x * 256 + threadIdx.x;
  if (e >= E) return;
  int s = src[e], d = dst[e];
  int pos = offs[d] + atomicAdd(&cursor[d], 1);
  csr[pos] = make_int2(s, __float_as_int(dinv[s] * dinv[d]));
}

// ---------------- aggregation (gather, CSR by dst), one wave per node ----------------
// 8-edge unroll, 4 accumulator chains; BN scale/shift of the previous layer is
// computed in an LDS prologue and applied per gathered row (fused, R11-style).

__device__ __forceinline__ void acc256(uint2 v, float co, float4 sc, float4 sh,
                                       float& ax, float& ay, float& az, float& aw) {
  float fx = fmaxf(bf2f((unsigned short)(v.x & 0xffff)) * sc.x + sh.x, 0.f);
  float fy = fmaxf(bf2f((unsigned short)(v.x >> 16)) * sc.y + sh.y, 0.f);
  float fz = fmaxf(bf2f((unsigned short)(v.y & 0xffff)) * sc.z + sh.z, 0.f);
  float fw = fmaxf(bf2f((unsigned short)(v.y >> 16)) * sc.w + sh.w, 0.f);
  ax += co * fx; ay += co * fy; az += co * fz; aw += co * fw;
}

__global__ __launch_bounds__(256) void agg256_bf(const unsigned short* __restrict__ h,
                                                 const int* __restrict__ offs,
                                                 const int2* __restrict__ csr,
                                                 const float* __restrict__ dinv,
                                                 const float* __restrict__ sums,
                                                 const float* __restrict__ sumsq,
                                                 const float* __restrict__ gamma,
                                                 const float* __restrict__ beta,
                                                 float invN,
                                                 unsigned short* __restrict__ out, int N) {
  __shared__ float s_sc[256], s_sh[256];
  {
    int c = threadIdx.x;
    float mean = sums[c] * invN;
    float var = sumsq[c] * invN - mean * mean;
    float scv = gamma[c] * rsqrtf(var + BN_EPS);
    s_sc[c] = scv;
    s_sh[c] = beta[c] - mean * scv;
  }
  __syncthreads();
  int n = (blockIdx.x * 256 + threadIdx.x) >> 6;
  int lane = threadIdx.x & 63;
  if (n >= N) return;
  float4 sc = *(const float4*)&s_sc[lane * 4];
  float4 sh = *(const float4*)&s_sh[lane * 4];
  float di = dinv[n];
  float self = di * di;
  float ax0 = 0.f, ay0 = 0.f, az0 = 0.f, aw0 = 0.f;
  float ax1 = 0.f, ay1 = 0.f, az1 = 0.f, aw1 = 0.f;
  float ax2 = 0.f, ay2 = 0.f, az2 = 0.f, aw2 = 0.f;
  float ax3 = 0.f, ay3 = 0.f, az3 = 0.f, aw3 = 0.f;
  {
    uint2 v = *((const uint2*)(h + (size_t)n * 256) + lane);
    acc256(v, self, sc, sh, ax0, ay0, az0, aw0);
  }
  int e0 = offs[n], e1 = offs[n + 1];
  for (int eb = e0; eb < e1; eb += 64) {
    int k = min(64, e1 - eb);
    int2 me = make_int2(0, 0);
    if (lane < k) me = csr[eb + lane];
    int i = 0;
    for (; i + 8 <= k; i += 8) {
      int s0 = __shfl(me.x, i),     s1 = __shfl(me.x, i + 1);
      int s2 = __shfl(me.x, i + 2), s3 = __shfl(me.x, i + 3);
      int s4 = __shfl(me.x, i + 4), s5 = __shfl(me.x, i + 5);
      int s6 = __shfl(me.x, i + 6), s7 = __shfl(me.x, i + 7);
      float c0 = __int_as_float(__shfl(me.y, i));
      float c1 = __int_as_float(__shfl(me.y, i + 1));
      float c2 = __int_as_float(__shfl(me.y, i + 2));
      float c3 = __int_as_float(__shfl(me.y, i + 3));
      float c4 = __int_as_float(__shfl(me.y, i + 4));
      float c5 = __int_as_float(__shfl(me.y, i + 5));
      float c6 = __int_as_float(__shfl(me.y, i + 6));
      float c7 = __int_as_float(__shfl(me.y, i + 7));
      uint2 v0 = *((const uint2*)(h + (size_t)s0 * 256) + lane);
      uint2 v1 = *((const uint2*)(h + (size_t)s1 * 256) + lane);
      uint2 v2 = *((const uint2*)(h + (size_t)s2 * 256) + lane);
      uint2 v3 = *((const uint2*)(h + (size_t)s3 * 256) + lane);
      uint2 v4 = *((const uint2*)(h + (size_t)s4 * 256) + lane);
      uint2 v5 = *((const uint2*)(h + (size_t)s5 * 256) + lane);
      uint2 v6 = *((const uint2*)(h + (size_t)s6 * 256) + lane);
      uint2 v7 = *((const uint2*)(h + (size_t)s7 * 256) + lane);
      acc256(v0, c0, sc, sh, ax0, ay0, az0, aw0);
      acc256(v1, c1, sc, sh, ax1, ay1, az1, aw1);
      acc256(v2, c2, sc, sh, ax2, ay2, az2, aw2);
      acc256(v3, c3, sc, sh, ax3, ay3, az3, aw3);
      acc256(v4, c4, sc, sh, ax0, ay0, az0, aw0);
      acc256(v5, c5, sc, sh, ax1, ay1, az1, aw1);
      acc256(v6, c6, sc, sh, ax2, ay2, az2, aw2);
      acc256(v7, c7, sc, sh, ax3, ay3, az3, aw3);
    }
    for (; i + 4 <= k; i += 4) {
      int s0 = __shfl(me.x, i),     s1 = __shfl(me.x, i + 1);
      int s2 = __shfl(me.x, i + 2), s3 = __shfl(me.x, i + 3);
      float c0 = __int_as_float(__shfl(me.y, i));
      float c1 = __int_as_float(__shfl(me.y, i + 1));
      float c2 = __int_as_float(__shfl(me.y, i + 2));
      float c3 = __int_as_float(__shfl(me.y, i + 3));
      uint2 v0 = *((const uint2*)(h + (size_t)s0 * 256) + lane);
      uint2 v1 = *((const uint2*)(h + (size_t)s1 * 256) + lane);
      uint2 v2 = *((const uint2*)(h + (size_t)s2 * 256) + lane);
      uint2 v3 = *((const uint2*)(h + (size_t)s3 * 256) + lane);
      acc256(v0, c0, sc, sh, ax0, ay0, az0, aw0);
      acc256(v1, c1, sc, sh, ax1, ay1, az1, aw1);
      acc256(v2, c2, sc, sh, ax2, ay2, az2, aw2);
      acc256(v3, c3, sc, sh, ax3, ay3, az3, aw3);
    }
    for (; i < k; ++i) {
      int s = __shfl(me.x, i);
      float co = __int_as_float(__shfl(me.y, i));
      uint2 v = *((const uint2*)(h + (size_t)s * 256) + lane);
      acc256(v, co, sc, sh, ax0, ay0, az0, aw0);
    }
  }
  float ax = (ax0 + ax1) + (ax2 + ax3), ay = (ay0 + ay1) + (ay2 + ay3);
  float az = (az0 + az1) + (az2 + az3), aw = (aw0 + aw1) + (aw2 + aw3);
  unsigned int lo = (unsigned int)f2bf(ax) | ((unsigned int)f2bf(ay) << 16);
  unsigned int hi = (unsigned int)f2bf(az) | ((unsigned int)f2bf(aw) << 16);
  *((uint2*)(out + (size_t)n * 256) + lane) = make_uint2(lo, hi);
}

__device__ __forceinline__ void acc128(unsigned int v, float co, float& ax, float& ay) {
  ax += co * bf2f((unsigned short)(v & 0xffff));
  ay += co * bf2f((unsigned short)(v >> 16));
}

__global__ __launch_bounds__(256) void agg128_bf(const unsigned short* __restrict__ h,
                                                 const int* __restrict__ offs,
                                                 const int2* __restrict__ csr,
                                                 const float* __restrict__ dinv,
                                                 unsigned short* __restrict__ out, int N) {
  int n = (blockIdx.x * 256 + threadIdx.x) >> 6;
  int lane = threadIdx.x & 63;
  if (n >= N) return;
  float di = dinv[n];
  float self = di * di;
  float ax0 = 0.f, ay0 = 0.f, ax1 = 0.f, ay1 = 0.f;
  float ax2 = 0.f, ay2 = 0.f, ax3 = 0.f, ay3 = 0.f;
  {
    unsigned int v = *((const unsigned int*)(h + (size_t)n * 128) + lane);
    acc128(v, self, ax0, ay0);
  }
  int e0 = offs[n], e1 = offs[n + 1];
  for (int eb = e0; eb < e1; eb += 64) {
    int k = min(64, e1 - eb);
    int2 me = make_int2(0, 0);
    if (lane < k) me = csr[eb + lane];
    int i = 0;
    for (; i + 8 <= k; i += 8) {
      int s0 = __shfl(me.x, i),     s1 = __shfl(me.x, i + 1);
      int s2 = __shfl(me.x, i + 2), s3 = __shfl(me.x, i + 3);
      int s4 = __shfl(me.x, i + 4), s5 = __shfl(me.x, i + 5);
      int s6 = __shfl(me.x, i + 6), s7 = __shfl(me.x, i + 7);
      float c0 = __int_as_float(__shfl(me.y, i));
      float c1 = __int_as_float(__shfl(me.y, i + 1));
      float c2 = __int_as_float(__shfl(me.y, i + 2));
      float c3 = __int_as_float(__shfl(me.y, i + 3));
      float c4 = __int_as_float(__shfl(me.y, i + 4));
      float c5 = __int_as_float(__shfl(me.y, i + 5));
      float c6 = __int_as_float(__shfl(me.y, i + 6));
      float c7 = __int_as_float(__shfl(me.y, i + 7));
      unsigned int v0 = *((const unsigned int*)(h + (size_t)s0 * 128) + lane);
      unsigned int v1 = *((const unsigned int*)(h + (size_t)s1 * 128) + lane);
      unsigned int v2 = *((const unsigned int*)(h + (size_t)s2 * 128) + lane);
      unsigned int v3 = *((const unsigned int*)(h + (size_t)s3 * 128) + lane);
      unsigned int v4 = *((const unsigned int*)(h + (size_t)s4 * 128) + lane);
      unsigned int v5 = *((const unsigned int*)(h + (size_t)s5 * 128) + lane);
      unsigned int v6 = *((const unsigned int*)(h + (size_t)s6 * 128) + lane);
      unsigned int v7 = *((const unsigned int*)(h + (size_t)s7 * 128) + lane);
      acc128(v0, c0, ax0, ay0); acc128(v1, c1, ax1, ay1);
      acc128(v2, c2, ax2, ay2); acc128(v3, c3, ax3, ay3);
      acc128(v4, c4, ax0, ay0); acc128(v5, c5, ax1, ay1);
      acc128(v6, c6, ax2, ay2); acc128(v7, c7, ax3, ay3);
    }
    for (; i + 4 <= k; i += 4) {
      int s0 = __shfl(me.x, i),     s1 = __shfl(me.x, i + 1);
      int s2 = __shfl(me.x, i + 2), s3 = __shfl(me.x, i + 3);
      float c0 = __int_as_float(__shfl(me.y, i));
      float c1 = __int_as_float(__shfl(me.y, i + 1));
      float c2 = __int_as_float(__shfl(me.y, i + 2));
      float c3 = __int_as_float(__shfl(me.y, i + 3));
      unsigned int v0 = *((const unsigned int*)(h + (size_t)s0 * 128) + lane);
      unsigned int v1 = *((const unsigned int*)(h + (size_t)s1 * 128) + lane);
      unsigned int v2 = *((const unsigned int*)(h + (size_t)s2 * 128) + lane);
      unsigned int v3 = *((const unsigned int*)(h + (size_t)s3 * 128) + lane);
      acc128(v0, c0, ax0, ay0); acc128(v1, c1, ax1, ay1);
      acc128(v2, c2, ax2, ay2); acc128(v3, c3, ax3, ay3);
    }
    for (; i < k; ++i) {
      int s = __shfl(me.x, i);
      float co = __int_as_float(__shfl(me.y, i));
      unsigned int v = *((const unsigned int*)(h + (size_t)s * 128) + lane);
      acc128(v, co, ax0, ay0);
    }
  }
  float ax = (ax0 + ax1) + (ax2 + ax3), ay = (ay0 + ay1) + (ay2 + ay3);
  *((unsigned int*)(out + (size_t)n * 128) + lane) =
      (unsigned int)f2bf(ax) | ((unsigned int)f2bf(ay) << 16);
}

// ---------------- bf16 MFMA GEMM + fused BN partial stats ----------------
// C[Mpad,256] = A[Mpad,K] @ W[K,256]; FULL-WIDTH tile 128x256, BK=64,
// 512 threads = 8 waves in 2 (row) x 4 (col) quadrants of 64x64 each.
// global_load_lds staging with XOR-pre-swizzled source + swizzled reads.
// Pad rows are zero -> no guards, exact-zero contribution to stats.

__global__ __launch_bounds__(512) void gemm_bf(const unsigned short* __restrict__ A,
                                               const unsigned short* __restrict__ Wt,
                                               unsigned short* __restrict__ C,
                                               int K,
                                               float* __restrict__ sums,
                                               float* __restrict__ sumsq) {
  __shared__ unsigned short As[128 * 64];   // 16 KB
  __shared__ unsigned short Bs[256 * 64];   // 32 KB
  int t = threadIdx.x;
  int w = t >> 6, lane = t & 63;
  int l16 = lane & 15, lhi = lane >> 4;
  int wr = w >> 2, wc = w & 3;              // 2x4 quadrants, each 64 rows x 64 cols
  int rowBase = blockIdx.x * 128;
  f32x4 acc[4][4] = {};
  int srow = lane >> 3;   // 0..7 within 8-row segment
  int sg = lane & 7;      // 16B group within 128B row
  const unsigned short* Abase = A + (size_t)rowBase * K;
  for (int k0 = 0; k0 < K; k0 += 64) {
#pragma unroll
    for (int r2 = 0; r2 < 2; ++r2) {
      int rb = r2 * 64 + w * 8;
      int row = rb + srow;
      int gg = sg ^ (row & 7);
      gload16(Abase + (size_t)row * K + k0 + gg * 8, &As[rb * 64]);
    }
#pragma unroll
    for (int r4 = 0; r4 < 4; ++r4) {
      int rb = r4 * 64 + w * 8;
      int row = rb + srow;
      int gg = sg ^ (row & 7);
      gload16(Wt + (size_t)row * K + k0 + gg * 8, &Bs[rb * 64]);
    }
    __syncthreads();
#pragma unroll
    for (int kk = 0; kk < 64; kk += 32) {
      int gb = (kk >> 3) + lhi;
      bf16x8 a[4], b[4];
#pragma unroll
      for (int i = 0; i < 4; ++i) {
        int ra = wr * 64 + i * 16 + l16;
        a[i] = *(const bf16x8*)&As[ra * 64 + ((gb ^ (ra & 7)) << 3)];
        int rb2 = wc * 64 + i * 16 + l16;
        b[i] = *(const bf16x8*)&Bs[rb2 * 64 + ((gb ^ (rb2 & 7)) << 3)];
      }
#pragma unroll
      for (int i = 0; i < 4; ++i)
#pragma unroll
        for (int j = 0; j < 4; ++j)
          acc[i][j] = __builtin_amdgcn_mfma_f32_16x16x32_bf16(a[i], b[j], acc[i][j], 0, 0, 0);
    }
    __syncthreads();
  }
#pragma unroll
  for (int i = 0; i < 4; ++i) {
#pragma unroll
    for (int rr = 0; rr < 4; ++rr) {
      int row = rowBase + wr * 64 + i * 16 + lhi * 4 + rr;
      size_t o = (size_t)row * 256 + wc * 64 + l16;
#pragma unroll
      for (int j = 0; j < 4; ++j) C[o + j * 16] = f2bf(acc[i][j][rr]);
    }
  }
#pragma unroll
  for (int j = 0; j < 4; ++j) {
    float s = 0.f, s2 = 0.f;
#pragma unroll
    for (int i = 0; i < 4; ++i)
#pragma unroll
      for (int rr = 0; rr < 4; ++rr) { float v = acc[i][j][rr]; s += v; s2 += v * v; }
    s  += __shfl_xor(s, 16);  s  += __shfl_xor(s, 32);
    s2 += __shfl_xor(s2, 16); s2 += __shfl_xor(s2, 32);
    if (lhi == 0) {
      int col = wc * 64 + j * 16 + l16;
      atomicAdd(&sums[col], s);
      atomicAdd(&sumsq[col], s2);
    }
  }
}

// ---------------- pool (BN2+ReLU fused, in-block finalize) + classifier ----------------

__global__ __launch_bounds__(256) void pool_final(const unsigned short* __restrict__ h,
                                                  const unsigned int* __restrict__ gstart,
                                                  const float* __restrict__ sums,
                                                  const float* __restrict__ sumsq,
                                                  const float* __restrict__ gamma,
                                                  const float* __restrict__ beta,
                                                  float invN,
                                                  const float* __restrict__ Wl,
                                                  const float* __restrict__ bl,
                                                  float* __restrict__ out, int NC) {
  __shared__ float s_sc[256], s_sh[256];
  __shared__ float4 part[4][64];
  __shared__ float p[256];
  int t = threadIdx.x, w = t >> 6, lane = t & 63;
  {
    float mean = sums[t] * invN;
    float var = sumsq[t] * invN - mean * mean;
    float scv = gamma[t] * rsqrtf(var + BN_EPS);
    s_sc[t] = scv;
    s_sh[t] = beta[t] - mean * scv;
  }
  __syncthreads();
  float4 sc = *(const float4*)&s_sc[lane * 4];
  float4 sh = *(const float4*)&s_sh[lane * 4];
  int g = blockIdx.x;
  int gs = (int)gstart[g], ge = (int)gstart[g + 1];
  float ax = 0.f, ay = 0.f, az = 0.f, aw = 0.f;
  for (int r = gs + w; r < ge; r += 4) {
    uint2 v = *((const uint2*)(h + (size_t)r * 256) + lane);
    ax += fmaxf(bf2f((unsigned short)(v.x & 0xffff)) * sc.x + sh.x, 0.f);
    ay += fmaxf(bf2f((unsigned short)(v.x >> 16)) * sc.y + sh.y, 0.f);
    az += fmaxf(bf2f((unsigned short)(v.y & 0xffff)) * sc.z + sh.z, 0.f);
    aw += fmaxf(bf2f((unsigned short)(v.y >> 16)) * sc.w + sh.w, 0.f);
  }
  part[w][lane] = make_float4(ax, ay, az, aw);
  __syncthreads();
  if (t < 64) {
    float inv = 1.0f / fmaxf((float)(ge - gs), 1.0f);
    float4 s0 = part[0][t], s1 = part[1][t], s2 = part[2][t], s3 = part[3][t];
    float4 r;
    r.x = (s0.x + s1.x + s2.x + s3.x) * inv;
    r.y = (s0.y + s1.y + s2.y + s3.y) * inv;
    r.z = (s0.z + s1.z + s2.z + s3.z) * inv;
    r.w = (s0.w + s1.w + s2.w + s3.w) * inv;
    *(float4*)&p[t * 4] = r;
  }
  __syncthreads();
  if (t < NC) {
    float s = bl[t];
    for (int k = 0; k < 256; ++k) s += p[k] * Wl[k * NC + t];
    out[g * NC + t] = s;
  }
}

// ---------------- launcher ----------------

extern "C" void kernel_launch(void* const* d_in, const int* in_sizes, int n_in,
                              void* d_out, int out_size, void* d_ws, size_t ws_size,
                              hipStream_t stream) {
  const float* x      = (const float*)d_in[0];
  const int*   ei     = (const int*)d_in[1];
  const int*   batch  = (const int*)d_in[2];
  const float* W0     = (const float*)d_in[3];
  const float* gamma0 = (const float*)d_in[5];
  const float* beta0  = (const float*)d_in[6];
  const float* W1     = (const float*)d_in[7];
  const float* gamma1 = (const float*)d_in[9];
  const float* beta1  = (const float*)d_in[10];
  const float* W2     = (const float*)d_in[11];
  const float* gamma2 = (const float*)d_in[13];
  const float* beta2  = (const float*)d_in[14];
  const float* Wl     = (const float*)d_in[15];
  const float* bl     = (const float*)d_in[16];
  float* out = (float*)d_out;

  int N = in_sizes[0] / 128;  // 50000
  int E = in_sizes[1] / 2;    // 800000
  int G = 128;
  int NC = 40;
  int Mpad = ((N + 127) / 128) * 128;  // 50048
  float invN = 1.0f / (float)N;
  const int* src = ei;
  const int* dst = ei + E;

  char* p = (char*)d_ws;
  auto alloc = [&](size_t bytes) -> void* {
    void* r = (void*)p;
    p += (bytes + 255) & ~(size_t)255;
    return r;
  };
  unsigned short* xb  = (unsigned short*)alloc((size_t)N * 128 * 2);
  unsigned short* hA  = (unsigned short*)alloc((size_t)Mpad * 256 * 2);
  unsigned short* hB  = (unsigned short*)alloc((size_t)Mpad * 256 * 2);
  unsigned short* Wt0 = (unsigned short*)alloc((size_t)256 * 128 * 2);
  unsigned short* Wt1 = (unsigned short*)alloc((size_t)256 * 256 * 2);
  unsigned short* Wt2 = (unsigned short*)alloc((size_t)256 * 256 * 2);
  int2*  csr      = (int2*) alloc((size_t)E * 8);
  int*   cc       = (int*)  alloc((size_t)(2 * N + 6 * 256) * 4);
  int*   counts   = cc;
  int*   cursor   = cc + N;
  float* stats    = (float*)(cc + 2 * N);
  float* sums0 = stats + 0 * 256, *sumsq0 = stats + 1 * 256;
  float* sums1 = stats + 2 * 256, *sumsq1 = stats + 3 * 256;
  float* sums2 = stats + 4 * 256, *sumsq2 = stats + 5 * 256;
  int*   offs     = (int*)  alloc((size_t)(N + 1) * 4);
  float* dinv     = (float*)alloc((size_t)N * 4);
  int*   blkSum   = (int*)  alloc(64 * 4);
  int*   blkOff   = (int*)  alloc(64 * 4);
  unsigned int* gstart = (unsigned int*)alloc((size_t)(G + 1) * 4);

  // ---- init ----
  hipMemsetAsync(cc, 0, (size_t)(2 * N + 6 * 256) * 4, stream);
  hipMemsetAsync(gstart, 0xFF, (size_t)(G + 1) * 4, stream);

  // ---- count + boundary + conversions + pad zeroing (one dispatch) ----
  {
    int nx4 = N * 32;
    int npad128_8 = (Mpad - N) * 128 / 8;
    int npad256_8 = (Mpad - N) * 256 / 8;
    long long total = (long long)E + nx4 + 128 * 256 + 256 * 256 + 256 * 256
                    + npad128_8 + npad256_8;
    int blocks = (int)((total + 255) / 256);
    count_cvt<<<blocks, 256, 0, stream>>>(dst, E, counts, batch, N, gstart,
                                          x, xb, nx4, W0, Wt0, W1, Wt1, W2, Wt2,
                                          hA + (size_t)N * 128, npad128_8,
                                          hA + (size_t)N * 256, npad256_8);
  }

  // ---- graph structure ----
  int nb = (N + 1023) / 1024;
  scan1<<<nb, 256, 0, stream>>>(counts, N, offs, blkSum, dinv);
  scan2_fix<<<1, 64, 0, stream>>>(blkSum, nb, blkOff, offs, N, gstart, G);
  scan3<<<nb, 1024, 0, stream>>>(offs, N, blkOff);
  fill_kernel<<<(E + 255) / 256, 256, 0, stream>>>(src, dst, E, offs, cursor, dinv, csr);

  int aggBlocks = (N + 3) / 4;
  int gemmBlocks = Mpad / 128;  // 391

  // ---- layer 0 ----
  agg128_bf<<<aggBlocks, 256, 0, stream>>>(xb, offs, csr, dinv, hA, N);
  gemm_bf<<<gemmBlocks, 512, 0, stream>>>(hA, Wt0, hB, 128, sums0, sumsq0);

  // ---- layer 1 (BN0 finalize + ReLU fused into gather prologue) ----
  agg256_bf<<<aggBlocks, 256, 0, stream>>>(hB, offs, csr, dinv, sums0, sumsq0,
                                           gamma0, beta0, invN, hA, N);
  gemm_bf<<<gemmBlocks, 512, 0, stream>>>(hA, Wt1, hB, 256, sums1, sumsq1);

  // ---- layer 2 ----
  agg256_bf<<<aggBlocks, 256, 0, stream>>>(hB, offs, csr, dinv, sums1, sumsq1,
                                           gamma1, beta1, invN, hA, N);
  gemm_bf<<<gemmBlocks, 512, 0, stream>>>(hA, Wt2, hB, 256, sums2, sumsq2);

  // ---- pool (BN2 finalize in-block) + classifier ----
  pool_final<<<G, 256, 0, stream>>>(hB, gstart, sums2, sumsq2, gamma2, beta2, invN,
                                    Wl, bl, out, NC);
}